// Round 1
// baseline (17.823 us; speedup 1.0000x reference)
//
#include <hip/hip_runtime.h>

// Quanv2d: 4-qubit circuit per patch, computed fully analytically in registers.
// One thread = one patch (b, r, c). 16-amplitude complex statevector in VGPRs.
//
// Circuit (N_LAYERS=1):
//   RY(pi*p_q) each qubit  -> real product amplitudes
//   CNOT((q+1)%4, q); RZ(W[3+q]); CNOT  == ZZ-diagonal phase
//   RX(W[3+q]) each qubit
//   z[q] = <Z_q>

#define TOTAL (128 * 63 * 63)   // B * R * C patches
#define PPI   3969              // 63*63 patches per image

__global__ __launch_bounds__(256)
void quanv_kernel(const float* __restrict__ X, const float* __restrict__ W,
                  float* __restrict__ out) {
    int tid = blockIdx.x * 256 + threadIdx.x;
    if (tid >= TOTAL) return;

    int b  = tid / PPI;
    int p  = tid - b * PPI;
    int r  = p / 63;
    int cc = p - r * 63;

    // X[b, 0, 2r, 2c + k], image stride = 3*128*128
    const float* xp = X + (size_t)b * (3 * 128 * 128) + (2 * r) * 128 + 2 * cc;
    float f0 = xp[0], f1 = xp[1], f2 = xp[2], f3 = xp[3];

    // RY half-angles: pi*p/2
    const float HPI = 1.5707963267948966f;
    float cq[4], sq[4];
    sincosf(HPI * f0, &sq[0], &cq[0]);
    sincosf(HPI * f1, &sq[1], &cq[1]);
    sincosf(HPI * f2, &sq[2], &cq[2]);
    sincosf(HPI * f3, &sq[3], &cq[3]);

    // weight half-angles (shared by ZZ phases and RX), indices 3..6
    float cth[4], sth[4];
#pragma unroll
    for (int q = 0; q < 4; ++q)
        sincosf(0.5f * W[3 + q], &sth[q], &cth[q]);

    // Build state after RY + ZZ-diagonal phases.
    // idx = b0*8 + b1*4 + b2*2 + b3 (qubit q <-> axis q+1, C-order flatten)
    float re[16], im[16];
#pragma unroll
    for (int idx = 0; idx < 16; ++idx) {
        int b0 = (idx >> 3) & 1, b1 = (idx >> 2) & 1;
        int b2 = (idx >> 1) & 1, b3 = idx & 1;
        float a = (b0 ? sq[0] : cq[0]) * (b1 ? sq[1] : cq[1]) *
                  (b2 ? sq[2] : cq[2]) * (b3 ? sq[3] : cq[3]);
        // e_q = +1 if b_ctrl == b_q (ctrl = (q+1)%4), phase factor per q:
        //   cos(th/2) - i*e_q*sin(th/2)
        float e0 = (b1 == b0) ? 1.f : -1.f;
        float e1 = (b2 == b1) ? 1.f : -1.f;
        float e2 = (b3 == b2) ? 1.f : -1.f;
        float e3 = (b0 == b3) ? 1.f : -1.f;
        float pr = cth[0], pj = -e0 * sth[0];
        float qr, qj, nr, nj;
        qr = cth[1]; qj = -e1 * sth[1];
        nr = pr * qr - pj * qj; nj = pr * qj + pj * qr; pr = nr; pj = nj;
        qr = cth[2]; qj = -e2 * sth[2];
        nr = pr * qr - pj * qj; nj = pr * qj + pj * qr; pr = nr; pj = nj;
        qr = cth[3]; qj = -e3 * sth[3];
        nr = pr * qr - pj * qj; nj = pr * qj + pj * qr; pr = nr; pj = nj;
        re[idx] = a * pr;
        im[idx] = a * pj;
    }

    // RX(W[3+q]) on qubit q; qubit q is bit (3-q) -> mask 8>>q.
    // RX = [[c, -i s], [-i s, c]]
#pragma unroll
    for (int q = 0; q < 4; ++q) {
        int mask = 8 >> q;
        float c = cth[q], s = sth[q];
#pragma unroll
        for (int i = 0; i < 16; ++i) {
            if (i & mask) continue;
            int j = i | mask;
            float x0 = re[i], y0 = im[i], x1 = re[j], y1 = im[j];
            re[i] = c * x0 + s * y1;
            im[i] = c * y0 - s * x1;
            re[j] = s * y0 + c * x1;
            im[j] = c * y1 - s * x0;
        }
    }

    // Z expectations
    float z0 = 0.f, z1 = 0.f, z2 = 0.f, z3 = 0.f;
#pragma unroll
    for (int i = 0; i < 16; ++i) {
        float prob = re[i] * re[i] + im[i] * im[i];
        z0 += ((i >> 3) & 1) ? -prob : prob;
        z1 += ((i >> 2) & 1) ? -prob : prob;
        z2 += ((i >> 1) & 1) ? -prob : prob;
        z3 += (i & 1) ? -prob : prob;
    }

    // out[b, p*4 + q] == out[tid*4 + q]; 16B-aligned -> float4 store
    reinterpret_cast<float4*>(out)[tid] = make_float4(z0, z1, z2, z3);
}

extern "C" void kernel_launch(void* const* d_in, const int* in_sizes, int n_in,
                              void* d_out, int out_size, void* d_ws, size_t ws_size,
                              hipStream_t stream) {
    const float* X = (const float*)d_in[0];
    const float* W = (const float*)d_in[1];
    float* out = (float*)d_out;
    int grid = (TOTAL + 255) / 256;  // 1985
    quanv_kernel<<<grid, 256, 0, stream>>>(X, W, out);
}

// Round 2
// 10.442 us; speedup vs baseline: 1.7067x; 1.7067x over previous
//
#include <hip/hip_runtime.h>

// Quanv2d — closed-form evaluation.
//
// Circuit algebra: RY(pi*f_q)|0> gives real product state; CNOT.RZ.CNOT is a
// diagonal ZZ phase; RX(th_q)^dag Z RX(th_q) = cos(th) Z + sin(th) Y. Summing
// over the product-state basis collapses to:
//   z_q = cos(th_q)*C_q + S_q*( sin^2(th_q)cos(th_{q-1})*C_{q+1}
//                             + sin(th_q)cos(th_q)sin(th_{q-1})*C_{q-1} )
// with C_q = cos(pi f_q), S_q = sin(pi f_q), th_q = W[3+q], indices mod 4.

#define TOTAL (128 * 63 * 63)   // B * 63 * 63 patches
#define PPI   3969              // 63*63 patches per image

__global__ __launch_bounds__(256)
void quanv_kernel(const float* __restrict__ X, const float* __restrict__ W,
                  float* __restrict__ out) {
    int tid = blockIdx.x * 256 + threadIdx.x;
    if (tid >= TOTAL) return;

    int b  = tid / PPI;
    int p  = tid - b * PPI;
    int r  = p / 63;
    int cc = p - r * 63;

    // X[b, 0, 2r, 2c + k]
    const float* xp = X + (size_t)b * (3 * 128 * 128) + (2 * r) * 128 + 2 * cc;
    float f0 = xp[0], f1 = xp[1], f2 = xp[2], f3 = xp[3];

    // C_j = cos(pi f_j) = cos(2pi * f_j/2); hardware trig takes revolutions.
    float C[4], S[4];
    C[0] = __builtin_amdgcn_cosf(0.5f * f0);
    S[0] = __builtin_amdgcn_sinf(0.5f * f0);
    C[1] = __builtin_amdgcn_cosf(0.5f * f1);
    S[1] = __builtin_amdgcn_sinf(0.5f * f1);
    C[2] = __builtin_amdgcn_cosf(0.5f * f2);
    S[2] = __builtin_amdgcn_sinf(0.5f * f2);
    C[3] = __builtin_amdgcn_cosf(0.5f * f3);
    S[3] = __builtin_amdgcn_sinf(0.5f * f3);

    // Uniform weight trig (full angles th in [0, 2pi) -> revolutions in [0,1)).
    const float INV2PI = 0.15915494309189535f;
    float sn[4], cs[4];
#pragma unroll
    for (int q = 0; q < 4; ++q) {
        float rev = W[3 + q] * INV2PI;
        sn[q] = __builtin_amdgcn_sinf(rev);
        cs[q] = __builtin_amdgcn_cosf(rev);
    }

    float z[4];
#pragma unroll
    for (int q = 0; q < 4; ++q) {
        int qm = (q + 3) & 3, qp = (q + 1) & 3;
        float E = sn[q] * sn[q] * cs[qm];   // sin^2(th_q) cos(th_{q-1})
        float F = sn[q] * cs[q] * sn[qm];   // sin(th_q) cos(th_q) sin(th_{q-1})
        z[q] = cs[q] * C[q] + S[q] * (E * C[qp] + F * C[qm]);
    }

    reinterpret_cast<float4*>(out)[tid] = make_float4(z[0], z[1], z[2], z[3]);
}

extern "C" void kernel_launch(void* const* d_in, const int* in_sizes, int n_in,
                              void* d_out, int out_size, void* d_ws, size_t ws_size,
                              hipStream_t stream) {
    const float* X = (const float*)d_in[0];
    const float* W = (const float*)d_in[1];
    float* out = (float*)d_out;
    int grid = (TOTAL + 255) / 256;  // 1985
    quanv_kernel<<<grid, 256, 0, stream>>>(X, W, out);
}

// Round 3
// 10.432 us; speedup vs baseline: 1.7084x; 1.0010x over previous
//
#include <hip/hip_runtime.h>

// Quanv2d — closed-form evaluation, division-free geometric grid mapping.
//
//   z_q = cos(th_q)*C_q + S_q*( sin^2(th_q)cos(th_{q-1})*C_{q+1}
//                             + sin(th_q)cos(th_q)sin(th_{q-1})*C_{q-1} )
// with C_q = cos(pi f_q), S_q = sin(pi f_q), th_q = W[3+q], indices mod 4.
//
// Grid: blockIdx.y = image b (128), blockIdx.x = row-group (16 x 4 rows),
// threadIdx.x: bits [7:6] = row-in-group, bits [5:0] = patch column cc.
// Lane cc=63 and row 63 are masked (63x63 patches). No integer division.

__global__ __launch_bounds__(256)
void quanv_kernel(const float* __restrict__ X, const float* __restrict__ W,
                  float* __restrict__ out) {
    int b  = blockIdx.y;
    int r  = (blockIdx.x << 2) | (threadIdx.x >> 6);
    int cc = threadIdx.x & 63;
    if (r >= 63 || cc >= 63) return;

    // X[b, 0, 2r, 2cc + k]; image stride 3*128*128 floats
    const float* xp = X + (size_t)b * 49152 + r * 256 + 2 * cc;
    float f0 = xp[0], f1 = xp[1], f2 = xp[2], f3 = xp[3];

    // C_j = cos(pi f_j); hardware trig takes revolutions (2*pi rad = 1.0).
    float C[4], S[4];
    C[0] = __builtin_amdgcn_cosf(0.5f * f0);
    S[0] = __builtin_amdgcn_sinf(0.5f * f0);
    C[1] = __builtin_amdgcn_cosf(0.5f * f1);
    S[1] = __builtin_amdgcn_sinf(0.5f * f1);
    C[2] = __builtin_amdgcn_cosf(0.5f * f2);
    S[2] = __builtin_amdgcn_sinf(0.5f * f2);
    C[3] = __builtin_amdgcn_cosf(0.5f * f3);
    S[3] = __builtin_amdgcn_sinf(0.5f * f3);

    // Uniform weight trig (angles in [0, 2pi) -> revolutions in [0,1)).
    const float INV2PI = 0.15915494309189535f;
    float sn[4], cs[4];
#pragma unroll
    for (int q = 0; q < 4; ++q) {
        float rev = W[3 + q] * INV2PI;
        sn[q] = __builtin_amdgcn_sinf(rev);
        cs[q] = __builtin_amdgcn_cosf(rev);
    }

    float z[4];
#pragma unroll
    for (int q = 0; q < 4; ++q) {
        int qm = (q + 3) & 3, qp = (q + 1) & 3;
        float E = sn[q] * sn[q] * cs[qm];   // sin^2(th_q) cos(th_{q-1})
        float F = sn[q] * cs[q] * sn[qm];   // sin(th_q) cos(th_q) sin(th_{q-1})
        z[q] = cs[q] * C[q] + S[q] * (E * C[qp] + F * C[qm]);
    }

    // out float4 index: b*3969 + r*63 + cc (contiguous per wave-row)
    int oi = b * 3969 + r * 63 + cc;
    reinterpret_cast<float4*>(out)[oi] = make_float4(z[0], z[1], z[2], z[3]);
}

extern "C" void kernel_launch(void* const* d_in, const int* in_sizes, int n_in,
                              void* d_out, int out_size, void* d_ws, size_t ws_size,
                              hipStream_t stream) {
    const float* X = (const float*)d_in[0];
    const float* W = (const float*)d_in[1];
    float* out = (float*)d_out;
    dim3 grid(16, 128);   // 16 row-groups x 128 images
    quanv_kernel<<<grid, 256, 0, stream>>>(X, W, out);
}